// Round 1
// baseline (521.801 us; speedup 1.0000x reference)
//
#include <hip/hip_runtime.h>
#include <hip/hip_bf16.h>

// AttGNN: GAT layer + GCN layer on sparse (~1%) 8192-node graph.
// Strategy: one pass over the 256 MB dense `sup` matrix to build a compact
// per-row (col, val) list; GAT softmax-aggregate and GCN aggregate then run
// on the ~17 MB compacted form (L2/L3-resident). Masked attention entries
// (-100 pre-softmax) contribute ~e^-100 and are dropped (threshold 1e-2).

#define N_NODES 8192
#define D_IN    128
#define D_GAT   64
#define SLOTS   256   // max nnz/row; binomial(8192,0.01) mean ~83, 19-sigma safe

// ---------------- K1: h = feat @ W_map ; s = h@U ; t = h@V ----------------
__global__ __launch_bounds__(64) void k1_map(
    const float* __restrict__ feat, const float* __restrict__ W_map,
    const float* __restrict__ U, const float* __restrict__ V,
    float* __restrict__ h, float* __restrict__ s, float* __restrict__ t)
{
    const int n = blockIdx.x;
    const int d = threadIdx.x;           // 0..63
    const float* frow = feat + n * D_IN;
    float acc = 0.f;
#pragma unroll 8
    for (int k = 0; k < D_IN; ++k)
        acc += frow[k] * W_map[k * D_GAT + d];   // frow broadcast, W_map coalesced
    h[n * D_GAT + d] = acc;
    float sv = acc * U[d];
    float tv = acc * V[d];
#pragma unroll
    for (int off = 32; off > 0; off >>= 1) {
        sv += __shfl_down(sv, off);
        tv += __shfl_down(tv, off);
    }
    if (d == 0) { s[n] = sv; t[n] = tv; }
}

// ---------------- K2: compact sup row -> (col, val=sup+diag) lists --------
__global__ __launch_bounds__(256) void k2_compact(
    const float* __restrict__ sup,
    int* __restrict__ cnt, int* __restrict__ col, float* __restrict__ val)
{
    const int j = blockIdx.x;
    __shared__ int c;
    if (threadIdx.x == 0) c = 0;
    __syncthreads();
    const float4* row = (const float4*)(sup + (size_t)j * N_NODES);
    int*   colj = col + j * SLOTS;
    float* valj = val + j * SLOTS;
    for (int q = threadIdx.x; q < N_NODES / 4; q += 256) {
        float4 v = row[q];
        const int i0 = q * 4;
        float vs[4] = {v.x, v.y, v.z, v.w};
#pragma unroll
        for (int u = 0; u < 4; ++u) {
            const int i = i0 + u;
            float vv = vs[u] + ((i == j) ? 1.0f : 0.0f);  // sup2 = sup + I
            if (vv > 0.f) {                               // matches sup2>0 mask
                int p = atomicAdd(&c, 1);
                if (p < SLOTS) { colj[p] = i; valj[p] = vv; }
            }
        }
    }
    __syncthreads();
    if (threadIdx.x == 0) cnt[j] = (c < SLOTS) ? c : SLOTS;
}

// ---------------- K3: GAT row: softmax(tanh(s_i+t_j+b)) aggregate over h --
__global__ __launch_bounds__(64) void k3_gat(
    const float* __restrict__ h, const float* __restrict__ s,
    const float* __restrict__ t, const float* __restrict__ b,
    const int* __restrict__ cnt, const int* __restrict__ col,
    const float* __restrict__ val, float* __restrict__ gat)
{
    const int j = blockIdx.x;
    const int lane = threadIdx.x;        // 0..63
    const int m = cnt[j];
    const int* colj = col + j * SLOTS;
    __shared__ float w[SLOTS];
    const float tj = t[j] + b[0];

    float lmax = -1e30f;
    for (int p = lane; p < m; p += 64) {
        float e = tanhf(s[colj[p]] + tj);
        w[p] = e;
        lmax = fmaxf(lmax, e);
    }
#pragma unroll
    for (int off = 32; off > 0; off >>= 1)
        lmax = fmaxf(lmax, __shfl_down(lmax, off));
    lmax = __shfl(lmax, 0);

    float lsum = 0.f;
    for (int p = lane; p < m; p += 64) {   // same p-set as writer: no barrier needed
        float e = __expf(w[p] - lmax);
        w[p] = e;
        lsum += e;
    }
#pragma unroll
    for (int off = 32; off > 0; off >>= 1) lsum += __shfl_down(lsum, off);
    lsum = __shfl(lsum, 0);
    __syncthreads();                       // all w[] visible before cross-lane read

    const float inv = 1.0f / lsum;
    float acc = 0.f;
    for (int p = 0; p < m; ++p)
        acc += w[p] * h[colj[p] * D_GAT + lane];  // h row gather, coalesced per p
    gat[j * D_GAT + lane] = tanhf(acc * inv);
}

// ---------------- K4: agg = sup2@gat ; out = normalize(relu(agg@W_gcn)) ---
__global__ __launch_bounds__(64) void k4_gcn(
    const float* __restrict__ gat, const float* __restrict__ W_gcn,
    const int* __restrict__ cnt, const int* __restrict__ col,
    const float* __restrict__ val, float* __restrict__ out)
{
    const int j = blockIdx.x;
    const int lane = threadIdx.x;
    const int m = cnt[j];
    const int*   colj = col + j * SLOTS;
    const float* valj = val + j * SLOTS;

    float agg = 0.f;
    for (int p = 0; p < m; ++p)
        agg += valj[p] * gat[colj[p] * D_GAT + lane];

    __shared__ float a[D_GAT];
    a[lane] = agg;
    __syncthreads();

    float o = 0.f;
#pragma unroll 8
    for (int d = 0; d < D_GAT; ++d)
        o += a[d] * W_gcn[d * D_GAT + lane];
    o = fmaxf(o, 0.f);

    float ss = o * o;
#pragma unroll
    for (int off = 32; off > 0; off >>= 1) ss += __shfl_down(ss, off);
    ss = __shfl(ss, 0);
    const float nrm = sqrtf(ss);
    out[j * D_GAT + lane] = o / fmaxf(nrm, 1e-12f);
}

extern "C" void kernel_launch(void* const* d_in, const int* in_sizes, int n_in,
                              void* d_out, int out_size, void* d_ws, size_t ws_size,
                              hipStream_t stream) {
    const float* feat  = (const float*)d_in[0];  // [N,128]
    const float* sup   = (const float*)d_in[1];  // [N,N]
    const float* W_map = (const float*)d_in[2];  // [128,64]
    const float* b_map = (const float*)d_in[3];  // [1]
    const float* U     = (const float*)d_in[4];  // [64,1]
    const float* V     = (const float*)d_in[5];  // [64,1]
    const float* W_gcn = (const float*)d_in[6];  // [64,64]
    float* out = (float*)d_out;

    // workspace carve-up (poisoned 0xAA before each call; all read-after-write)
    char* ws = (char*)d_ws;
    float* h   = (float*)(ws);                         // 2 MB
    float* gat = (float*)(ws + (2u << 20));            // 2 MB
    float* s   = (float*)(ws + (4u << 20));            // 32 KB
    float* t   = (float*)(ws + (4u << 20) + 32768);    // 32 KB
    int*   cnt = (int*)  (ws + (4u << 20) + 65536);    // 32 KB
    int*   col = (int*)  (ws + (4u << 20) + 98304);    // 8 MB
    float* val = (float*)(ws + (12u << 20) + 98304);   // 8 MB  (total ~20.1 MB)

    k1_map   <<<N_NODES,  64, 0, stream>>>(feat, W_map, U, V, h, s, t);
    k2_compact<<<N_NODES, 256, 0, stream>>>(sup, cnt, col, val);
    k3_gat   <<<N_NODES,  64, 0, stream>>>(h, s, t, b_map, cnt, col, val, gat);
    k4_gcn   <<<N_NODES,  64, 0, stream>>>(gat, W_gcn, cnt, col, val, out);
}

// Round 2
// 412.071 us; speedup vs baseline: 1.2663x; 1.2663x over previous
//
#include <hip/hip_runtime.h>
#include <hip/hip_bf16.h>

// AttGNN: GAT + GCN on sparse (~1%) 8192-node graph.
// R1: ballot-based compaction (K2), float4 lane-split gathers (K3/K4),
// LDS-staged feat rows (K1). True floor = one 256 MB read of `sup` (~41 us).

#define N_NODES 8192
#define D_IN    128
#define D_GAT   64
#define SLOTS   256   // max nnz/row; binomial(8192,0.01) mean ~83, max ~120

// ---------------- K1: h = feat @ W_map ; s = h@U ; t = h@V ----------------
// 4 rows/block, 256 threads; wave w handles row blockIdx*4+w; lane = d.
__global__ __launch_bounds__(256) void k1_map(
    const float* __restrict__ feat, const float* __restrict__ W_map,
    const float* __restrict__ U, const float* __restrict__ V,
    float* __restrict__ h, float* __restrict__ s, float* __restrict__ t)
{
    const int r = threadIdx.x >> 6;        // wave id = local row
    const int d = threadIdx.x & 63;
    const int row = blockIdx.x * 4 + r;
    __shared__ float f[4 * D_IN];          // 2 KB
    if (threadIdx.x < 128)                 // 512 floats = 128 float4
        ((float4*)f)[threadIdx.x] =
            ((const float4*)(feat + (size_t)blockIdx.x * 4 * D_IN))[threadIdx.x];
    __syncthreads();

    const float* fr = f + r * D_IN;
    float acc = 0.f;
#pragma unroll 8
    for (int k = 0; k < D_IN; ++k)
        acc += fr[k] * W_map[k * D_GAT + d];   // fr broadcast (LDS), W_map L1-hot
    h[row * D_GAT + d] = acc;

    float sv = acc * U[d];
    float tv = acc * V[d];
#pragma unroll
    for (int off = 32; off > 0; off >>= 1) {
        sv += __shfl_xor(sv, off);
        tv += __shfl_xor(tv, off);
    }
    if (d == 0) { s[row] = sv; t[row] = tv; }
}

// ---------------- K2: compact sup row -> (col, val=sup+diag) lists --------
// Wave-level ballot compaction: 1 LDS atomic per wave-slice, coalesced-ish writes.
__global__ __launch_bounds__(256) void k2_compact(
    const float* __restrict__ sup,
    int* __restrict__ cnt, int* __restrict__ col, float* __restrict__ val)
{
    const int j = blockIdx.x;
    const int lane = threadIdx.x & 63;
    __shared__ int c;
    if (threadIdx.x == 0) c = 0;
    __syncthreads();
    const float4* row = (const float4*)(sup + (size_t)j * N_NODES);
    int*   colj = col + j * SLOTS;
    float* valj = val + j * SLOTS;

    for (int q = threadIdx.x; q < N_NODES / 4; q += 256) {
        float4 v = row[q];
        const int i0 = q * 4;
        float vs[4] = {v.x, v.y, v.z, v.w};
#pragma unroll
        for (int u = 0; u < 4; ++u) {
            const int i = i0 + u;
            const float vv = vs[u] + ((i == j) ? 1.0f : 0.0f);  // sup2 = sup + I
            const bool keep = vv > 0.f;
            const unsigned long long mask = __ballot(keep);
            if (mask) {                                   // wave-uniform branch
                int base = 0;
                if (lane == 0) base = atomicAdd(&c, __popcll(mask));
                base = __shfl(base, 0);
                if (keep) {
                    const int pos = base +
                        __popcll(mask & ((1ull << lane) - 1ull));
                    if (pos < SLOTS) { colj[pos] = i; valj[pos] = vv; }
                }
            }
        }
    }
    __syncthreads();
    if (threadIdx.x == 0) cnt[j] = (c < SLOTS) ? c : SLOTS;
}

// ---------------- K3: GAT row: softmax(tanh(s_i+t_j+b)) aggregate over h --
// One wave/row. Gather phase: lane=(pp,c), pp=lane>>4 picks neighbor,
// c=lane&15 picks float4 quarter of the 64-wide h row -> 16 B/lane coalesced.
__global__ __launch_bounds__(64) void k3_gat(
    const float* __restrict__ h, const float* __restrict__ s,
    const float* __restrict__ t, const float* __restrict__ b,
    const int* __restrict__ cnt, const int* __restrict__ col,
    float* __restrict__ gat)
{
    const int j = blockIdx.x;
    const int lane = threadIdx.x;
    const int m = cnt[j];
    const int* colj = col + j * SLOTS;
    __shared__ int   cl[SLOTS];
    __shared__ float w[SLOTS];
    const float tj = t[j] + b[0];

    float lmax = -1e30f;
    for (int p = lane; p < m; p += 64) {
        const int ci = colj[p];
        cl[p] = ci;
        const float e = tanhf(s[ci] + tj);
        w[p] = e;
        lmax = fmaxf(lmax, e);
    }
#pragma unroll
    for (int off = 32; off > 0; off >>= 1)
        lmax = fmaxf(lmax, __shfl_xor(lmax, off));

    float lsum = 0.f;
    for (int p = lane; p < m; p += 64) {   // same p-set as writer
        const float e = __expf(w[p] - lmax);
        w[p] = e;
        lsum += e;
    }
#pragma unroll
    for (int off = 32; off > 0; off >>= 1) lsum += __shfl_xor(lsum, off);
    __syncthreads();                       // w[], cl[] visible across lanes

    const int c16 = (lane & 15) * 4;       // float4 column offset
    const int pp  = lane >> 4;             // 0..3: neighbor sub-slot
    float4 acc = make_float4(0.f, 0.f, 0.f, 0.f);
    for (int base = 0; base < m; base += 4) {
        const int p = base + pp;
        if (p < m) {
            const float wp = w[p];
            const float4 hv = *(const float4*)(h + cl[p] * D_GAT + c16);
            acc.x += wp * hv.x; acc.y += wp * hv.y;
            acc.z += wp * hv.z; acc.w += wp * hv.w;
        }
    }
#pragma unroll
    for (int off = 16; off <= 32; off <<= 1) {   // reduce across pp groups
        acc.x += __shfl_xor(acc.x, off); acc.y += __shfl_xor(acc.y, off);
        acc.z += __shfl_xor(acc.z, off); acc.w += __shfl_xor(acc.w, off);
    }
    if (pp == 0) {
        const float inv = 1.0f / lsum;
        float4 o;
        o.x = tanhf(acc.x * inv); o.y = tanhf(acc.y * inv);
        o.z = tanhf(acc.z * inv); o.w = tanhf(acc.w * inv);
        *(float4*)(gat + j * D_GAT + c16) = o;
    }
}

// ---------------- K4: agg = sup2@gat ; out = normalize(relu(agg@W_gcn)) ---
__global__ __launch_bounds__(64) void k4_gcn(
    const float* __restrict__ gat, const float* __restrict__ W_gcn,
    const int* __restrict__ cnt, const int* __restrict__ col,
    const float* __restrict__ val, float* __restrict__ out)
{
    const int j = blockIdx.x;
    const int lane = threadIdx.x;
    const int m = cnt[j];
    const int*   colj = col + j * SLOTS;
    const float* valj = val + j * SLOTS;
    __shared__ int   cl[SLOTS];
    __shared__ float wv[SLOTS];
    for (int p = lane; p < m; p += 64) { cl[p] = colj[p]; wv[p] = valj[p]; }
    __syncthreads();

    const int c16 = (lane & 15) * 4;
    const int pp  = lane >> 4;
    float4 acc = make_float4(0.f, 0.f, 0.f, 0.f);
    for (int base = 0; base < m; base += 4) {
        const int p = base + pp;
        if (p < m) {
            const float wp = wv[p];
            const float4 gv = *(const float4*)(gat + cl[p] * D_GAT + c16);
            acc.x += wp * gv.x; acc.y += wp * gv.y;
            acc.z += wp * gv.z; acc.w += wp * gv.w;
        }
    }
#pragma unroll
    for (int off = 16; off <= 32; off <<= 1) {
        acc.x += __shfl_xor(acc.x, off); acc.y += __shfl_xor(acc.y, off);
        acc.z += __shfl_xor(acc.z, off); acc.w += __shfl_xor(acc.w, off);
    }
    __shared__ float a[D_GAT];
    if (pp == 0) *(float4*)(a + c16) = acc;
    __syncthreads();

    float o = 0.f;
#pragma unroll 8
    for (int d = 0; d < D_GAT; ++d)
        o += a[d] * W_gcn[d * D_GAT + lane];   // a broadcast, W_gcn L1-hot
    o = fmaxf(o, 0.f);

    float ss = o * o;
#pragma unroll
    for (int off = 32; off > 0; off >>= 1) ss += __shfl_xor(ss, off);
    const float nrm = sqrtf(ss);
    out[j * D_GAT + lane] = o / fmaxf(nrm, 1e-12f);
}

extern "C" void kernel_launch(void* const* d_in, const int* in_sizes, int n_in,
                              void* d_out, int out_size, void* d_ws, size_t ws_size,
                              hipStream_t stream) {
    const float* feat  = (const float*)d_in[0];  // [N,128]
    const float* sup   = (const float*)d_in[1];  // [N,N]
    const float* W_map = (const float*)d_in[2];  // [128,64]
    const float* b_map = (const float*)d_in[3];  // [1]
    const float* U     = (const float*)d_in[4];  // [64,1]
    const float* V     = (const float*)d_in[5];  // [64,1]
    const float* W_gcn = (const float*)d_in[6];  // [64,64]
    float* out = (float*)d_out;

    char* ws = (char*)d_ws;
    float* h   = (float*)(ws);                         // 2 MB
    float* gat = (float*)(ws + (2u << 20));            // 2 MB
    float* s   = (float*)(ws + (4u << 20));            // 32 KB
    float* t   = (float*)(ws + (4u << 20) + 32768);    // 32 KB
    int*   cnt = (int*)  (ws + (4u << 20) + 65536);    // 32 KB
    int*   col = (int*)  (ws + (4u << 20) + 98304);    // 8 MB
    float* val = (float*)(ws + (12u << 20) + 98304);   // 8 MB  (~20.1 MB total)

    k1_map    <<<N_NODES / 4, 256, 0, stream>>>(feat, W_map, U, V, h, s, t);
    k2_compact<<<N_NODES,     256, 0, stream>>>(sup, cnt, col, val);
    k3_gat    <<<N_NODES,      64, 0, stream>>>(h, s, t, b_map, cnt, col, gat);
    k4_gcn    <<<N_NODES,      64, 0, stream>>>(gat, W_gcn, cnt, col, val, out);
}

// Round 3
// 408.776 us; speedup vs baseline: 1.2765x; 1.0081x over previous
//
#include <hip/hip_runtime.h>
#include <hip/hip_bf16.h>

// AttGNN: GAT + GCN on sparse (~1%) 8192-node graph.
// R2: fuse K1 under K2's HBM shadow; 4 rows/block + unroll-4 multi-outstanding
// gathers in K3/K4. True floor = one 256 MB read of `sup` (~41 us) + fixed
// harness reset cost (~240 us of poison-fill/restore visible in dur_us).

#define N_NODES 8192
#define D_IN    128
#define D_GAT   64
#define SLOTS   256          // max nnz/row; binomial(8192,0.01) mean ~83, max ~120
#define K1_BLOCKS (N_NODES / 4)   // 2048 blocks of 4 rows

// ---------------- K12: [blocks 0..2047] h=feat@W_map, s=h@U, t=h@V
//                  [blocks 2048..10239] compact sup row -> (col,val) ----------
__global__ __launch_bounds__(256) void k12_map_compact(
    const float* __restrict__ feat, const float* __restrict__ W_map,
    const float* __restrict__ U, const float* __restrict__ V,
    const float* __restrict__ sup,
    float* __restrict__ h, float* __restrict__ s, float* __restrict__ t,
    int* __restrict__ cnt, int* __restrict__ col, float* __restrict__ val)
{
    if (blockIdx.x < K1_BLOCKS) {
        // ---- K1 part: 4 rows per block, wave r handles row blockIdx*4+r ----
        const int r = threadIdx.x >> 6;
        const int d = threadIdx.x & 63;
        const int row = blockIdx.x * 4 + r;
        __shared__ float f[4 * D_IN];
        if (threadIdx.x < 128)
            ((float4*)f)[threadIdx.x] =
                ((const float4*)(feat + (size_t)blockIdx.x * 4 * D_IN))[threadIdx.x];
        __syncthreads();
        const float* fr = f + r * D_IN;
        float acc = 0.f;
#pragma unroll 8
        for (int k = 0; k < D_IN; ++k)
            acc += fr[k] * W_map[k * D_GAT + d];
        h[row * D_GAT + d] = acc;
        float sv = acc * U[d];
        float tv = acc * V[d];
#pragma unroll
        for (int off = 32; off > 0; off >>= 1) {
            sv += __shfl_xor(sv, off);
            tv += __shfl_xor(tv, off);
        }
        if (d == 0) { s[row] = sv; t[row] = tv; }
    } else {
        // ---- K2 part: ballot compaction of row j ----
        const int j = blockIdx.x - K1_BLOCKS;
        const int lane = threadIdx.x & 63;
        __shared__ int c;
        if (threadIdx.x == 0) c = 0;
        __syncthreads();
        const float4* row = (const float4*)(sup + (size_t)j * N_NODES);
        int*   colj = col + j * SLOTS;
        float* valj = val + j * SLOTS;
        for (int q = threadIdx.x; q < N_NODES / 4; q += 256) {
            float4 v = row[q];
            const int i0 = q * 4;
            float vs[4] = {v.x, v.y, v.z, v.w};
#pragma unroll
            for (int u = 0; u < 4; ++u) {
                const int i = i0 + u;
                const float vv = vs[u] + ((i == j) ? 1.0f : 0.0f); // sup2=sup+I
                const bool keep = vv > 0.f;
                const unsigned long long mask = __ballot(keep);
                if (mask) {                                   // wave-uniform
                    int base = 0;
                    if (lane == 0) base = atomicAdd(&c, __popcll(mask));
                    base = __shfl(base, 0);
                    if (keep) {
                        const int pos = base +
                            __popcll(mask & ((1ull << lane) - 1ull));
                        if (pos < SLOTS) { colj[pos] = i; valj[pos] = vv; }
                    }
                }
            }
        }
        __syncthreads();
        if (threadIdx.x == 0) cnt[j] = (c < SLOTS) ? c : SLOTS;
    }
}

// ---------------- K3: GAT row: softmax(tanh(s_i+t_j+b)) aggregate over h ----
// 4 rows/block (one wave each). Gather: lane=(pp,c16): pp=lane>>4 neighbor
// sub-slot, c16 float4 column; unroll-4 -> 4 outstanding loads.
__global__ __launch_bounds__(256) void k3_gat(
    const float* __restrict__ h, const float* __restrict__ s,
    const float* __restrict__ t, const float* __restrict__ b,
    const int* __restrict__ cnt, const int* __restrict__ col,
    float* __restrict__ gat)
{
    const int wid  = threadIdx.x >> 6;
    const int lane = threadIdx.x & 63;
    const int j = blockIdx.x * 4 + wid;
    const int m = cnt[j];
    const int* colj = col + j * SLOTS;
    __shared__ int   cl_s[4][SLOTS];
    __shared__ float w_s[4][SLOTS];
    int*   cl = cl_s[wid];
    float* w  = w_s[wid];
    const float tj = t[j] + b[0];

    float lmax = -1e30f;
    for (int p = lane; p < m; p += 64) {
        const int ci = colj[p];
        cl[p] = ci;
        const float e = tanhf(s[ci] + tj);
        w[p] = e;
        lmax = fmaxf(lmax, e);
    }
#pragma unroll
    for (int off = 32; off > 0; off >>= 1)
        lmax = fmaxf(lmax, __shfl_xor(lmax, off));

    float lsum = 0.f;
    for (int p = lane; p < m; p += 64) {   // same p-set as writer
        const float e = __expf(w[p] - lmax);
        w[p] = e;
        lsum += e;
    }
#pragma unroll
    for (int off = 32; off > 0; off >>= 1) lsum += __shfl_xor(lsum, off);
    __syncthreads();                       // w[], cl[] visible across lanes

    const int c16 = (lane & 15) * 4;
    const int pp  = lane >> 4;
    float4 a0 = make_float4(0,0,0,0), a1 = a0, a2 = a0, a3 = a0;
    for (int base = 0; base < m; base += 16) {
        const int p0 = base + pp, p1 = p0 + 4, p2 = p0 + 8, p3 = p0 + 12;
        if (p0 < m) { const float wp = w[p0];
            const float4 v = *(const float4*)(h + cl[p0] * D_GAT + c16);
            a0.x += wp*v.x; a0.y += wp*v.y; a0.z += wp*v.z; a0.w += wp*v.w; }
        if (p1 < m) { const float wp = w[p1];
            const float4 v = *(const float4*)(h + cl[p1] * D_GAT + c16);
            a1.x += wp*v.x; a1.y += wp*v.y; a1.z += wp*v.z; a1.w += wp*v.w; }
        if (p2 < m) { const float wp = w[p2];
            const float4 v = *(const float4*)(h + cl[p2] * D_GAT + c16);
            a2.x += wp*v.x; a2.y += wp*v.y; a2.z += wp*v.z; a2.w += wp*v.w; }
        if (p3 < m) { const float wp = w[p3];
            const float4 v = *(const float4*)(h + cl[p3] * D_GAT + c16);
            a3.x += wp*v.x; a3.y += wp*v.y; a3.z += wp*v.z; a3.w += wp*v.w; }
    }
    float4 acc;
    acc.x = (a0.x + a1.x) + (a2.x + a3.x);
    acc.y = (a0.y + a1.y) + (a2.y + a3.y);
    acc.z = (a0.z + a1.z) + (a2.z + a3.z);
    acc.w = (a0.w + a1.w) + (a2.w + a3.w);
#pragma unroll
    for (int off = 16; off <= 32; off <<= 1) {
        acc.x += __shfl_xor(acc.x, off); acc.y += __shfl_xor(acc.y, off);
        acc.z += __shfl_xor(acc.z, off); acc.w += __shfl_xor(acc.w, off);
    }
    if (pp == 0) {
        const float inv = 1.0f / lsum;
        float4 o;
        o.x = tanhf(acc.x * inv); o.y = tanhf(acc.y * inv);
        o.z = tanhf(acc.z * inv); o.w = tanhf(acc.w * inv);
        *(float4*)(gat + j * D_GAT + c16) = o;
    }
}

// ---------------- K4: agg = sup2@gat ; out = normalize(relu(agg@W_gcn)) ----
__global__ __launch_bounds__(256) void k4_gcn(
    const float* __restrict__ gat, const float* __restrict__ W_gcn,
    const int* __restrict__ cnt, const int* __restrict__ col,
    const float* __restrict__ val, float* __restrict__ out)
{
    const int wid  = threadIdx.x >> 6;
    const int lane = threadIdx.x & 63;
    const int j = blockIdx.x * 4 + wid;
    const int m = cnt[j];
    const int*   colj = col + j * SLOTS;
    const float* valj = val + j * SLOTS;
    __shared__ int   cl_s[4][SLOTS];
    __shared__ float wv_s[4][SLOTS];
    __shared__ float a_s[4][D_GAT];
    int*   cl = cl_s[wid];
    float* wv = wv_s[wid];
    float* a  = a_s[wid];
    for (int p = lane; p < m; p += 64) { cl[p] = colj[p]; wv[p] = valj[p]; }
    __syncthreads();

    const int c16 = (lane & 15) * 4;
    const int pp  = lane >> 4;
    float4 a0 = make_float4(0,0,0,0), a1 = a0, a2 = a0, a3 = a0;
    for (int base = 0; base < m; base += 16) {
        const int p0 = base + pp, p1 = p0 + 4, p2 = p0 + 8, p3 = p0 + 12;
        if (p0 < m) { const float wp = wv[p0];
            const float4 v = *(const float4*)(gat + cl[p0] * D_GAT + c16);
            a0.x += wp*v.x; a0.y += wp*v.y; a0.z += wp*v.z; a0.w += wp*v.w; }
        if (p1 < m) { const float wp = wv[p1];
            const float4 v = *(const float4*)(gat + cl[p1] * D_GAT + c16);
            a1.x += wp*v.x; a1.y += wp*v.y; a1.z += wp*v.z; a1.w += wp*v.w; }
        if (p2 < m) { const float wp = wv[p2];
            const float4 v = *(const float4*)(gat + cl[p2] * D_GAT + c16);
            a2.x += wp*v.x; a2.y += wp*v.y; a2.z += wp*v.z; a2.w += wp*v.w; }
        if (p3 < m) { const float wp = wv[p3];
            const float4 v = *(const float4*)(gat + cl[p3] * D_GAT + c16);
            a3.x += wp*v.x; a3.y += wp*v.y; a3.z += wp*v.z; a3.w += wp*v.w; }
    }
    float4 acc;
    acc.x = (a0.x + a1.x) + (a2.x + a3.x);
    acc.y = (a0.y + a1.y) + (a2.y + a3.y);
    acc.z = (a0.z + a1.z) + (a2.z + a3.z);
    acc.w = (a0.w + a1.w) + (a2.w + a3.w);
#pragma unroll
    for (int off = 16; off <= 32; off <<= 1) {
        acc.x += __shfl_xor(acc.x, off); acc.y += __shfl_xor(acc.y, off);
        acc.z += __shfl_xor(acc.z, off); acc.w += __shfl_xor(acc.w, off);
    }
    if (pp == 0) *(float4*)(a + c16) = acc;
    __syncthreads();     // a_s visibility (intra-wave, but keep it simple/safe)

    float o = 0.f;
#pragma unroll 8
    for (int d = 0; d < D_GAT; ++d)
        o += a[d] * W_gcn[d * D_GAT + lane];   // a broadcast, W_gcn L1-hot
    o = fmaxf(o, 0.f);

    float ss = o * o;
#pragma unroll
    for (int off = 32; off > 0; off >>= 1) ss += __shfl_xor(ss, off);
    const float nrm = sqrtf(ss);
    out[j * D_GAT + lane] = o / fmaxf(nrm, 1e-12f);
}

extern "C" void kernel_launch(void* const* d_in, const int* in_sizes, int n_in,
                              void* d_out, int out_size, void* d_ws, size_t ws_size,
                              hipStream_t stream) {
    const float* feat  = (const float*)d_in[0];  // [N,128]
    const float* sup   = (const float*)d_in[1];  // [N,N]
    const float* W_map = (const float*)d_in[2];  // [128,64]
    const float* b_map = (const float*)d_in[3];  // [1]
    const float* U     = (const float*)d_in[4];  // [64,1]
    const float* V     = (const float*)d_in[5];  // [64,1]
    const float* W_gcn = (const float*)d_in[6];  // [64,64]
    float* out = (float*)d_out;

    char* ws = (char*)d_ws;
    float* h   = (float*)(ws);                         // 2 MB
    float* gat = (float*)(ws + (2u << 20));            // 2 MB
    float* s   = (float*)(ws + (4u << 20));            // 32 KB
    float* t   = (float*)(ws + (4u << 20) + 32768);    // 32 KB
    int*   cnt = (int*)  (ws + (4u << 20) + 65536);    // 32 KB
    int*   col = (int*)  (ws + (4u << 20) + 98304);    // 8 MB
    float* val = (float*)(ws + (12u << 20) + 98304);   // 8 MB  (~20.1 MB total)

    k12_map_compact<<<K1_BLOCKS + N_NODES, 256, 0, stream>>>(
        feat, W_map, U, V, sup, h, s, t, cnt, col, val);
    k3_gat<<<N_NODES / 4, 256, 0, stream>>>(h, s, t, b_map, cnt, col, gat);
    k4_gcn<<<N_NODES / 4, 256, 0, stream>>>(gat, W_gcn, cnt, col, val, out);
}